// Round 5
// baseline (169.414 us; speedup 1.0000x reference)
//
#include <hip/hip_runtime.h>

typedef unsigned short US;
typedef __bf16 bf16x8 __attribute__((ext_vector_type(8)));
typedef float f32x4 __attribute__((ext_vector_type(4)));

__device__ __forceinline__ US f2bf(float f) {
  union { float f; unsigned u; } v; v.f = f;
  unsigned r = v.u + 0x7fffu + ((v.u >> 16) & 1u);
  return (US)(r >> 16);
}

// ---------------- kernel 0: pw_w fp32 -> bf16 ----------------
__global__ __launch_bounds__(256) void k_convw(const float* __restrict__ pw,
                                               US* __restrict__ wb) {
  int i = (blockIdx.x * 256 + threadIdx.x) * 4;
  float4 v = *(const float4*)(pw + i);
  ushort4 s;
  s.x = f2bf(v.x); s.y = f2bf(v.y); s.z = f2bf(v.z); s.w = f2bf(v.w);
  *(ushort4*)(wb + i) = s;
}

// ---------------- kernel 1: depthwise 7x7 -> y8 [b][c/8][px][8c] ----------------
// 512 blocks (16 b x 32 cg); 8 waves/block = 8 channels; each wave covers the
// full 64x64 plane of its channel: 64 lanes = 16 col-strips x 4 row-bands,
// vertical 7-row register sliding window over 16 rows per band.
__global__ __launch_bounds__(512, 4) void k_dw(const float* __restrict__ x,
                                               const float* __restrict__ dww,
                                               const float* __restrict__ dwb,
                                               US* __restrict__ y8) {
  const int bid = blockIdx.x;           // 16b * 32cg
  const int cg  = bid & 31;
  const int b   = bid >> 5;
  const int t   = threadIdx.x;
  const int w   = t >> 6;               // wave id = channel slot 0..7
  const int l   = t & 63;
  const int s   = l & 15;               // col strip (4 cols)
  const int band = l >> 4;              // row band (16 rows)
  const int c   = __builtin_amdgcn_readfirstlane(cg * 8 + w);  // wave-uniform
  const float* xp = x + ((size_t)b * 256 + c) * 4096;
  float wv[49];
  const float* wp = dww + c * 49;       // scalar base -> s_load
#pragma unroll
  for (int i = 0; i < 49; ++i) wv[i] = wp[i];
  const float bias = dwb[c];

  const int bcx   = s * 4;              // output col base
  const int rbase = band * 16;          // output row base

  __shared__ US t8[8][4096];

  float win[7][12];                     // rows idx%7, cols bcx-4..bcx+7
  const float4 fz = {0.f, 0.f, 0.f, 0.f};

  // row loader: L[i] = x[r][bcx-4+i], zero outside the image
#define LOADROW(Ldst, r)                                                     \
  do {                                                                       \
    if ((unsigned)(r) < 64u) {                                               \
      const float* rp = xp + (r) * 64 + bcx;                                 \
      float4 a_ = (bcx >= 4) ? *(const float4*)(rp - 4) : fz;                \
      float4 b_ = *(const float4*)(rp);                                      \
      float4 c_ = (bcx < 60) ? *(const float4*)(rp + 4) : fz;                \
      (Ldst)[0] = a_.x; (Ldst)[1] = a_.y; (Ldst)[2]  = a_.z; (Ldst)[3]  = a_.w; \
      (Ldst)[4] = b_.x; (Ldst)[5] = b_.y; (Ldst)[6]  = b_.z; (Ldst)[7]  = b_.w; \
      (Ldst)[8] = c_.x; (Ldst)[9] = c_.y; (Ldst)[10] = c_.z; (Ldst)[11] = c_.w; \
    } else {                                                                 \
      _Pragma("unroll")                                                      \
      for (int z_ = 0; z_ < 12; ++z_) (Ldst)[z_] = 0.f;                      \
    }                                                                        \
  } while (0)

  // prologue: input rows rbase-3 .. rbase+2 (idx 0..5)
#pragma unroll
  for (int idx = 0; idx < 6; ++idx) LOADROW(win[idx], rbase - 3 + idx);

#pragma unroll
  for (int o = 0; o < 16; ++o) {
    // incoming input row rbase+o+3 (idx o+6) -> slot (o+6)%7
    LOADROW(win[(o + 6) % 7], rbase + o + 3);
    float a0 = bias, a1 = bias, a2 = bias, a3 = bias;
#pragma unroll
    for (int kh = 0; kh < 7; ++kh) {
      const float* L = win[(o + kh) % 7];   // input row rbase+o-3+kh
#pragma unroll
      for (int kw = 0; kw < 7; ++kw) {
        const float wk = wv[kh * 7 + kw];
        a0 = fmaf(L[kw + 1], wk, a0);
        a1 = fmaf(L[kw + 2], wk, a1);
        a2 = fmaf(L[kw + 3], wk, a2);
        a3 = fmaf(L[kw + 4], wk, a3);
      }
    }
    ushort4 sv;
    sv.x = f2bf(a0); sv.y = f2bf(a1); sv.z = f2bf(a2); sv.w = f2bf(a3);
    *(ushort4*)&t8[w][(rbase + o) * 64 + bcx] = sv;
  }
  __syncthreads();

  // pack epilogue: y8[b][cg][px][8c]; lane t covers px pairs -> 32B contiguous
  const size_t ybase = ((size_t)b * 32 + cg) * 4096;
#pragma unroll
  for (int it = 0; it < 4; ++it) {
    const int px = it * 1024 + t * 2;
    unsigned rc[8];
#pragma unroll
    for (int c2 = 0; c2 < 8; ++c2) rc[c2] = *(const unsigned*)&t8[c2][px];
    uint4 A, B2;
    A.x  = __builtin_amdgcn_perm(rc[1], rc[0], 0x05040100u);  // even px: c0,c1
    A.y  = __builtin_amdgcn_perm(rc[3], rc[2], 0x05040100u);
    A.z  = __builtin_amdgcn_perm(rc[5], rc[4], 0x05040100u);
    A.w  = __builtin_amdgcn_perm(rc[7], rc[6], 0x05040100u);
    B2.x = __builtin_amdgcn_perm(rc[1], rc[0], 0x07060302u);  // odd px
    B2.y = __builtin_amdgcn_perm(rc[3], rc[2], 0x07060302u);
    B2.z = __builtin_amdgcn_perm(rc[5], rc[4], 0x07060302u);
    B2.w = __builtin_amdgcn_perm(rc[7], rc[6], 0x07060302u);
    US* yb = y8 + (ybase + px) * 8;
    *(uint4*)(yb)     = A;
    *(uint4*)(yb + 8) = B2;
  }
#undef LOADROW
}

// ---------------- kernel 2: pointwise GEMM (MFMA bf16) ----------------
// out^T fragments via swapped operands; double-buffered LDS; XCD swizzle.
// per batch: out[512][4096] = W(512x256) x Y^T ; tile 128o x 128px, BK=64
__global__ __launch_bounds__(256, 2) void k_pw(const US* __restrict__ y8,
                                               const US* __restrict__ wb,
                                               const float* __restrict__ pwb,
                                               float* __restrict__ out) {
  // bijective XCD swizzle (nwg=2048, %8==0): chunk of 256 per XCD
  const int bid = blockIdx.x;
  const int s   = ((bid & 7) << 8) | (bid >> 3);
  const int b   = s >> 7;
  const int rr  = s & 127;
  const int nt  = rr >> 2;        // px tile (32)
  const int mt  = rr & 3;         // o tile (4) innermost -> y8-tile L2 reuse
  const int o0  = mt * 128;
  const int hw0 = nt * 128;

  __shared__ US lsA[2][128][72];
  __shared__ US lsB[2][128][72];
  const int tid  = threadIdx.x;
  const int lane = tid & 63;
  const int wid  = tid >> 6;
  const int wm   = wid >> 1, wn = wid & 1;
  const int strow = tid >> 3;     // A-stage: 0..31
  const int scg   = tid & 7;      // A-stage: 16B chunk within 128B k-row
  const int bg    = tid >> 5;     // B-stage: 8c-group 0..7
  const int bl    = tid & 31;     // B-stage: px within group of 32

  const f32x4 fzero = {0.f, 0.f, 0.f, 0.f};
  f32x4 acc[4][4];
#pragma unroll
  for (int m = 0; m < 4; ++m)
#pragma unroll
    for (int n = 0; n < 4; ++n) acc[m][n] = fzero;

  uint4 ra[4], rb[4];
  // prologue: stage kt=0 into buffer 0
#pragma unroll
  for (int i = 0; i < 4; ++i) {
    ra[i] = *(const uint4*)(wb + (size_t)(o0 + i * 32 + strow) * 256 + scg * 8);
    rb[i] = *(const uint4*)(y8 + ((size_t)(b * 32 + bg) * 4096 + hw0 + bl + 32 * i) * 8);
  }
#pragma unroll
  for (int i = 0; i < 4; ++i) {
    *(uint4*)&lsA[0][i * 32 + strow][scg * 8] = ra[i];
    *(uint4*)&lsB[0][bl + 32 * i][bg * 8]     = rb[i];
  }
  __syncthreads();

  for (int kt = 0; kt < 4; ++kt) {
    const int cur = kt & 1;
    // issue-early: global loads for next tile (hide under compute)
    if (kt < 3) {
      const int ck = (kt + 1) * 64;
#pragma unroll
      for (int i = 0; i < 4; ++i) {
        ra[i] = *(const uint4*)(wb + (size_t)(o0 + i * 32 + strow) * 256 + ck + scg * 8);
        rb[i] = *(const uint4*)(y8 + ((size_t)(b * 32 + (ck >> 3) + bg) * 4096 + hw0 + bl + 32 * i) * 8);
      }
    }
    bf16x8 af[2][4], bfr[2][4];
#pragma unroll
    for (int kk = 0; kk < 2; ++kk) {
      const int kcol = kk * 32 + (lane >> 4) * 8;
#pragma unroll
      for (int m = 0; m < 4; ++m)
        af[kk][m] = *reinterpret_cast<const bf16x8*>(&lsA[cur][wm * 64 + m * 16 + (lane & 15)][kcol]);
#pragma unroll
      for (int n = 0; n < 4; ++n)
        bfr[kk][n] = *reinterpret_cast<const bf16x8*>(&lsB[cur][wn * 64 + n * 16 + (lane & 15)][kcol]);
    }
#pragma unroll
    for (int kk = 0; kk < 2; ++kk)
#pragma unroll
      for (int m = 0; m < 4; ++m)
#pragma unroll
        for (int n = 0; n < 4; ++n)
          // swapped operands: acc = (Y^T)*(W^T) = out^T fragment
          acc[m][n] = __builtin_amdgcn_mfma_f32_16x16x32_bf16(bfr[kk][n], af[kk][m], acc[m][n], 0, 0, 0);

    if (kt < 3) {
#pragma unroll
      for (int i = 0; i < 4; ++i) {
        *(uint4*)&lsA[cur ^ 1][i * 32 + strow][scg * 8] = ra[i];
        *(uint4*)&lsB[cur ^ 1][bl + 32 * i][bg * 8]     = rb[i];
      }
      __syncthreads();
    }
  }

  // epilogue: D^T layout -> lane holds 4 consecutive px at fixed o: dwordx4 stores
#pragma unroll
  for (int m = 0; m < 4; ++m) {
    const int o  = o0 + wm * 64 + m * 16 + (lane & 15);
    const float bv = pwb[o];
    float* orow = out + (((size_t)b * 512 + o) * 4096) + hw0 + wn * 64 + (lane >> 4) * 4;
#pragma unroll
    for (int n = 0; n < 4; ++n) {
      f32x4 v = acc[m][n];
      v[0] += bv; v[1] += bv; v[2] += bv; v[3] += bv;
      __builtin_nontemporal_store(v, (f32x4*)(orow + n * 16));
    }
  }
}

extern "C" void kernel_launch(void* const* d_in, const int* in_sizes, int n_in,
                              void* d_out, int out_size, void* d_ws, size_t ws_size,
                              hipStream_t stream) {
  const float* x   = (const float*)d_in[0];
  const float* dww = (const float*)d_in[1];
  const float* dwb = (const float*)d_in[2];
  const float* pww = (const float*)d_in[3];
  const float* pwb = (const float*)d_in[4];
  float* out = (float*)d_out;

  char* ws = (char*)d_ws;
  US* y8  = (US*)ws;                         // 16*32*4096*8 bf16 = 33,554,432 B
  US* wbf = (US*)(ws + 33554432);            // 512*256 bf16 = 262,144 B

  k_convw<<<128, 256, 0, stream>>>(pww, wbf);
  k_dw   <<<512, 512, 0, stream>>>(x, dww, dwb, y8);
  k_pw   <<<2048, 256, 0, stream>>>(y8, wbf, pwb, out);
}